// Round 16
// baseline (749.800 us; speedup 1.0000x reference)
//
#include <hip/hip_runtime.h>
#include <hip/hip_bf16.h>
#include <math.h>

#define IN_DIM 128
#define PRE_HID 256
#define HID 16
#define NRANGE 8

__device__ __forceinline__ float lrelu(float v) { return v > 0.f ? v : 0.01f * v; }
__device__ __forceinline__ float fin(float v) { return (v == v && fabsf(v) < 1e30f) ? v : 0.f; }

__device__ __forceinline__ float ldp(const void* p, size_t i, int f32) {
    if (f32) return ((const float*)p)[i];
    unsigned u = ((const unsigned short*)p)[i];
    return __uint_as_float(u << 16);
}
__device__ __forceinline__ unsigned short f2bf(float f) {
    union { __hip_bfloat16 b; unsigned short u; } cv;
    cv.b = __float2bfloat16(f);
    return cv.u;
}
__device__ __forceinline__ void unpack8(uint4 u, float* o) {
    o[0] = __uint_as_float(u.x << 16); o[1] = __uint_as_float(u.x & 0xFFFF0000u);
    o[2] = __uint_as_float(u.y << 16); o[3] = __uint_as_float(u.y & 0xFFFF0000u);
    o[4] = __uint_as_float(u.z << 16); o[5] = __uint_as_float(u.z & 0xFFFF0000u);
    o[6] = __uint_as_float(u.w << 16); o[7] = __uint_as_float(u.w & 0xFFFF0000u);
}
__device__ __forceinline__ unsigned pk2(float a, float b) {
    return (unsigned)f2bf(a) | ((unsigned)f2bf(b) << 16);
}
__device__ __forceinline__ uint4 pack8(const float* v) {
    uint4 u;
    u.x = pk2(v[0], v[1]); u.y = pk2(v[2], v[3]);
    u.z = pk2(v[4], v[5]); u.w = pk2(v[6], v[7]);
    return u;
}

// ---- fixed small-param region (float offsets)
#define OFF_W1F   0          // fp32 [32768]  (w1q: k-major [32][256][4])
#define OFF_B1F   32768      // fp32 [256]
#define OFF_W2T   33024      // fp32 [4096]   (w2t: [256][16])
#define OFF_B2F   37120      // fp32 [16]
#define OFF_HW    37136      // fp32 [2][256]
#define OFF_GCNB  37648      // fp32 [2][16]
#define OFF_POST  37680      // fp32 [34] (+pad)
#define OFF_FLAGS 37720      // int [2]: [0]=int64 edges, [1]=fp32 floats
#define OFF_BSUM  37760      // uint [128]
#define OFF_BPRE  37888      // uint [128]
#define OFF_A0    38016      // N-dependent regions start here

// ---------------- dtype detection ----------------
__global__ void k_detect(const unsigned short* __restrict__ xu,
                         const int* __restrict__ ei32, int* __restrict__ flags) {
    if (threadIdx.x == 0 && blockIdx.x == 0) {
        int band = 0;
        for (int k = 0; k < 128; ++k) {
            unsigned e = (xu[2 * k] >> 7) & 0xFF;
            if (e >= 100 && e <= 140) band++;
        }
        flags[1] = (band < 96) ? 1 : 0;  // low in-band => fp32 data
        int any = 0;
        for (int k = 0; k < 64; ++k) any |= ei32[2 * k + 1];
        flags[0] = (any == 0) ? 1 : 0;   // all-zero odd slots => int64
    }
}

__global__ void k_sentinel(unsigned* __restrict__ out, int words, unsigned val) {
    int i = blockIdx.x * 256 + threadIdx.x;
    if (i < words) out[i] = val;
}

// ---------------- small params ----------------
__global__ void k_prep_small(const void* __restrict__ bih, const void* __restrict__ bhh,
                             const void* __restrict__ wtW, const void* __restrict__ wtb,
                             const void* __restrict__ p1W, const void* __restrict__ p1b,
                             const void* __restrict__ paW, const void* __restrict__ pab,
                             const int* __restrict__ flags,
                             float* __restrict__ hw, float* __restrict__ post) {
    int f32 = flags[1];
    __shared__ float mem[2][16];
    int t = threadIdx.x;
    if (t < 32) {
        int l = t >> 4, j = t & 15;
        float bi0 = ldp(bih, l * 48 + j, f32),      bh0 = ldp(bhh, l * 48 + j, f32);
        float bi1 = ldp(bih, l * 48 + 16 + j, f32), bh1 = ldp(bhh, l * 48 + 16 + j, f32);
        float bi2 = ldp(bih, l * 48 + 32 + j, f32), bh2 = ldp(bhh, l * 48 + 32 + j, f32);
        float r = 1.f / (1.f + expf(-(bi0 + bh0)));
        float z = 1.f / (1.f + expf(-(bi1 + bh1)));
        float nn = tanhf(bi2 + r * bh2);
        mem[l][j] = (1.f - z) * nn;
    }
    __syncthreads();
    for (int l = 0; l < 2; ++l) {
        float acc = ldp(wtb, l * 256 + t, f32);
        #pragma unroll
        for (int m = 0; m < 16; ++m)
            acc += ldp(wtW, l * 4096 + t * 16 + m, f32) * mem[l][m];
        hw[l * 256 + t] = acc;
    }
    if (t < 16) {
        post[t]      = ldp(p1W, t, f32) + ldp(p1W, 16 + t, f32);
        post[17 + t] = ldp(paW, t, f32);
    }
    if (t == 0) {
        post[16] = ldp(p1b, 0, f32) + ldp(p1b, 1, f32);
        post[33] = ldp(pab, 0, f32);
    }
}

__global__ void k_convert(const void* __restrict__ p1W, const void* __restrict__ p1b,
                          const void* __restrict__ p2W, const void* __restrict__ p2b,
                          const void* __restrict__ gcnb, const int* __restrict__ flags,
                          float* __restrict__ w1q, float* __restrict__ b1f,
                          float* __restrict__ w2t, float* __restrict__ b2f,
                          float* __restrict__ gcnbf) {
    int f32 = flags[1];
    int i = blockIdx.x * 256 + threadIdx.x;
    // w1q[kq][r][i2] = W1[r][4*kq + i2]  (k-major float4 rows for grouped loads)
    if (i < 32768) {
        int i2 = i & 3, r = (i >> 2) & 255, kq = i >> 10;
        w1q[i] = ldp(p1W, (size_t)r * 128 + kq * 4 + i2, f32);
    }
    if (i < 256)   b1f[i] = ldp(p1b, i, f32);
    if (i < 4096)  { int r = i >> 4, j = i & 15; w2t[i] = ldp(p2W, j * 256 + r, f32); }
    if (i < 16)    b2f[i] = ldp(p2b, i, f32);
    if (i < 32)    gcnbf[i] = ldp(gcnb, i, f32);
}

// ---------------- degree: ONE edge scan, 8-way replicated histogram ---------
__global__ void k_deg_rep(const int* __restrict__ ei, const int* __restrict__ flags,
                          unsigned* __restrict__ degr, int E, int N) {
    int e = blockIdx.x * 256 + threadIdx.x;
    if (e >= E) return;
    int rep = blockIdx.x & (NRANGE - 1);
    int d = flags[0] ? ei[2 * ((size_t)E + e)] : ei[(size_t)E + e];
    if ((unsigned)d < (unsigned)N) atomicAdd(&degr[(size_t)rep * N + d], 1u);
}

// legacy ranged version (fallback path only)
__global__ void k_deg(const int* __restrict__ ei, const int* __restrict__ flags,
                      unsigned* __restrict__ deg, int E, int N) {
    int rid = blockIdx.x & (NRANGE - 1);
    int e = (blockIdx.x >> 3) * 256 + threadIdx.x;
    if (e >= E) return;
    int R = (N + NRANGE - 1) / NRANGE;
    int lo = rid * R;
    int hi = lo + R; if (hi > N) hi = N;
    int d = flags[0] ? ei[2 * ((size_t)E + e)] : ei[(size_t)E + e];
    if (d >= lo && d < hi) atomicAdd(&deg[d], 1u);
}

__global__ void k_dinv(float* __restrict__ degdinv, int N) {
    int n = blockIdx.x * 256 + threadIdx.x;
    if (n >= N) return;
    unsigned dg = ((unsigned*)degdinv)[n];
    degdinv[n] = 1.f / sqrtf((float)dg + 1.f);
}

// ---------------- prefix scan ----------------
// scan_block sums the 8 degree replicas and materializes deg[i]
__global__ __launch_bounds__(1024) void k_scan_block(const unsigned* __restrict__ degr,
                                                     unsigned* __restrict__ deg,
                                                     unsigned* __restrict__ bsum, int N) {
    __shared__ unsigned s[1024];
    int t = threadIdx.x;
    int i = blockIdx.x * 1024 + t;
    unsigned v = 0u;
    if (i < N) {
        #pragma unroll
        for (int r = 0; r < NRANGE; ++r) v += degr[(size_t)r * N + i];
        deg[i] = v;
    }
    s[t] = v;
    __syncthreads();
    for (int off = 512; off > 0; off >>= 1) {
        if (t < off) s[t] += s[t + off];
        __syncthreads();
    }
    if (t == 0) bsum[blockIdx.x] = s[0];
}

__global__ __launch_bounds__(128) void k_scan_top(unsigned* __restrict__ bsum,
                                                  unsigned* __restrict__ bpre, int NB) {
    __shared__ unsigned s[128];
    int t = threadIdx.x;
    unsigned v = (t < NB) ? bsum[t] : 0u;
    s[t] = v;
    __syncthreads();
    for (int off = 1; off < 128; off <<= 1) {
        unsigned a = (t >= off) ? s[t - off] : 0u;
        __syncthreads();
        s[t] += a;
        __syncthreads();
    }
    if (t < NB) bpre[t] = s[t] - v;
}

// scan_final emits rowptr (= segment START, exclusive prefix) and dinv
__global__ __launch_bounds__(1024) void k_scan_final(const unsigned* __restrict__ deg,
                                                     const unsigned* __restrict__ bpre,
                                                     unsigned* __restrict__ rowptr,
                                                     float* __restrict__ dinv, int N) {
    __shared__ unsigned s[1024];
    int t = threadIdx.x;
    int i = blockIdx.x * 1024 + t;
    unsigned v = (i < N) ? deg[i] : 0u;
    s[t] = v;
    __syncthreads();
    for (int off = 1; off < 1024; off <<= 1) {
        unsigned a = (t >= off) ? s[t - off] : 0u;
        __syncthreads();
        s[t] += a;
        __syncthreads();
    }
    if (i < N) {
        rowptr[i] = bpre[blockIdx.x] + s[t] - v;
        dinv[i] = 1.f / sqrtf((float)v + 1.f);
    }
}

// ---------------- replica sub-segment cursors ----------------
// rowptr_rep[r][n] = rowptr[n] + sum_{r'<r} degr[r'][n]. Because k_fill_rep
// uses the SAME edge->rep mapping as k_deg_rep, replica r writes exactly
// degr[r][n] entries to node n -> sub-segments partition the CSR segment,
// positions globally unique. rowptr itself stays = segment start.
__global__ void k_rowrep(const unsigned* __restrict__ rowptr,
                         const unsigned* __restrict__ degr,
                         unsigned* __restrict__ rowptr_rep, int N) {
    int n = blockIdx.x * 256 + threadIdx.x;
    if (n >= N) return;
    unsigned base = rowptr[n];
    #pragma unroll
    for (int r = 0; r < NRANGE; ++r) {
        rowptr_rep[(size_t)r * N + n] = base;
        base += degr[(size_t)r * N + n];
    }
}

// ---------------- CSR fill: ONE edge scan, replicated cursors ---------------
// Single pass (3.2M threads vs 25.6M): block b bumps cursor replica b&7 —
// L2-local atomics via round-robin block->XCD dispatch; edge reads 230->51MB.
__global__ void k_fill_rep(const int* __restrict__ ei, const int* __restrict__ flags,
                           unsigned* __restrict__ rowptr_rep, unsigned* __restrict__ csr,
                           int E, int N) {
    int e = blockIdx.x * 256 + threadIdx.x;
    if (e >= E) return;
    int rep = blockIdx.x & (NRANGE - 1);
    int d, s;
    if (flags[0]) { s = ei[2 * (size_t)e]; d = ei[2 * ((size_t)E + e)]; }
    else          { s = ei[e];             d = ei[(size_t)E + e]; }
    if ((unsigned)d >= (unsigned)N) return;
    if ((unsigned)s >= (unsigned)N) s = d;
    unsigned pos = atomicAdd(&rowptr_rep[(size_t)rep * N + d], 1u);
    csr[pos] = (unsigned)s;
}

// legacy ranged fill (kept for reference; unused)
__global__ void k_fill(const int* __restrict__ ei, const int* __restrict__ flags,
                       unsigned* __restrict__ rowptr, unsigned* __restrict__ csr,
                       int E, int N) {
    int rid = blockIdx.x & (NRANGE - 1);
    int e = (blockIdx.x >> 3) * 256 + threadIdx.x;
    if (e >= E) return;
    int R = (N + NRANGE - 1) / NRANGE;
    int lo = rid * R;
    int hi = lo + R; if (hi > N) hi = N;
    int d = flags[0] ? ei[2 * ((size_t)E + e)] : ei[(size_t)E + e];
    if (d < lo || d >= hi) return;
    int s = flags[0] ? ei[2 * (size_t)e] : ei[e];
    if ((unsigned)s >= (unsigned)N) s = d;
    unsigned pos = atomicAdd(&rowptr[d], 1u);
    csr[pos] = (unsigned)s;
}

// ---------------- preprocess: 8-wave cooperative LDS tile (R9 form) ----------
__global__ __launch_bounds__(512) void k_pre_lds(const void* __restrict__ x,
                                                 const float* __restrict__ w1q,
                                                 const float* __restrict__ b1f,
                                                 const float* __restrict__ w2t,
                                                 const float* __restrict__ b2f,
                                                 const int* __restrict__ flags,
                                                 float* __restrict__ h, int N) {
    __shared__ __align__(16) float smem[8320];      // 32.5 KB: xs (65-pad), red overlay
    const int t = threadIdx.x;
    const int l = t & 63;
    const int wu = __builtin_amdgcn_readfirstlane(t >> 6);  // 0..7, wave-uniform
    const int nb0 = blockIdx.x * 64;
    const int f32 = flags[1];

    // ---- stage x[nb0..nb0+63][:] -> xs[kq][node][4]  (smem[(kq*65+n)*4 + i])
    {
        int n = t >> 3;                 // staged node 0..63
        int gn = nb0 + n; if (gn >= N) gn = N - 1;
        if (f32) {
            int c0 = (t & 7) * 4;       // this thread's 4 k-quads
            const float4* gx = reinterpret_cast<const float4*>((const float*)x + (size_t)gn * IN_DIM);
            #pragma unroll
            for (int j = 0; j < 4; ++j) {
                float4 v = gx[c0 + j];
                *reinterpret_cast<float4*>(&smem[((c0 + j) * 65 + n) * 4]) = v;
            }
        } else {
            const uint4* gx = reinterpret_cast<const uint4*>((const unsigned short*)x + (size_t)gn * IN_DIM);
            #pragma unroll
            for (int jj = 0; jj < 2; ++jj) {
                int j = (t & 7) * 2 + jj;       // uint4 index 0..15
                float o[8];
                unpack8(gx[j], o);
                float4 v0, v1;
                v0.x = o[0]; v0.y = o[1]; v0.z = o[2]; v0.w = o[3];
                v1.x = o[4]; v1.y = o[5]; v1.z = o[6]; v1.w = o[7];
                *reinterpret_cast<float4*>(&smem[((j * 2) * 65 + n) * 4]) = v0;
                *reinterpret_cast<float4*>(&smem[((j * 2 + 1) * 65 + n) * 4]) = v1;
            }
        }
    }
    __syncthreads();

    // ---- layer 1: wave's 32 rows, kq-outer so one xv read feeds 128 FMAs
    const int rr = wu * 32;                       // wave-uniform row base
    float s[32];
    #pragma unroll
    for (int r = 0; r < 32; ++r) s[r] = b1f[rr + r];

    #pragma unroll 1
    for (int kq = 0; kq < 32; ++kq) {
        float4 xv = *reinterpret_cast<const float4*>(&smem[(kq * 65 + l) * 4]);
        const float4* wq = reinterpret_cast<const float4*>(w1q + ((size_t)kq * 256 + rr) * 4);
        {
            float4 w[16];
            #pragma unroll
            for (int r = 0; r < 16; ++r) w[r] = wq[r];       // grouped s_loads
            #pragma unroll
            for (int r = 0; r < 16; ++r)
                s[r] += w[r].x * xv.x + w[r].y * xv.y + w[r].z * xv.z + w[r].w * xv.w;
        }
        {
            float4 w[16];
            #pragma unroll
            for (int r = 0; r < 16; ++r) w[r] = wq[16 + r];
            #pragma unroll
            for (int r = 0; r < 16; ++r)
                s[16 + r] += w[r].x * xv.x + w[r].y * xv.y + w[r].z * xv.z + w[r].w * xv.w;
        }
    }

    // ---- layer 2 fold over this wave's 32 rows
    float acc2[16];
    #pragma unroll
    for (int j = 0; j < 16; ++j) acc2[j] = 0.f;
    #pragma unroll
    for (int r = 0; r < 32; ++r) {
        float tv = lrelu(s[r]);
        const float* w2r = w2t + (size_t)(rr + r) * HID;     // wave-uniform
        #pragma unroll
        for (int j = 0; j < 16; ++j) acc2[j] += w2r[j] * tv;
    }
    __syncthreads();                  // xs dead from here; red overlays it

    // ---- cross-wave reduction via overlaid red[j][wave][node] (conflict-free)
    #pragma unroll
    for (int j = 0; j < 16; ++j) smem[(j * 8 + wu) * 64 + l] = acc2[j];
    __syncthreads();

    // ---- reduce 8 wave partials, bias + lrelu, store h[64][16] (threads 0..255)
    if (t < 256) {
        int n = t & 63, jq = t >> 6;
        int gn = nb0 + n;
        if (gn < N) {
            float o[4];
            #pragma unroll
            for (int i = 0; i < 4; ++i) {
                int j = jq * 4 + i;
                float v = 0.f;
                #pragma unroll
                for (int w = 0; w < 8; ++w) v += smem[(j * 8 + w) * 64 + n];
                o[i] = lrelu(v + b2f[j]);
            }
            float4 v; v.x = o[0]; v.y = o[1]; v.z = o[2]; v.w = o[3];
            *reinterpret_cast<float4*>(h + (size_t)gn * HID + jq * 4) = v;
        }
    }
}

// ---------------- CSR path: y = (h @ W^T) * dinv[n] ----------------
__global__ void k_xw_y(const float* __restrict__ h, const float* __restrict__ W,
                       const float* __restrict__ dinv, float* __restrict__ y, int N) {
    int n = blockIdx.x * 256 + threadIdx.x;
    if (n >= N) return;
    float hv[HID];
    const float4* hp = reinterpret_cast<const float4*>(h + (size_t)n * HID);
    #pragma unroll
    for (int q = 0; q < 4; ++q) {
        float4 v = hp[q];
        hv[q*4+0] = v.x; hv[q*4+1] = v.y; hv[q*4+2] = v.z; hv[q*4+3] = v.w;
    }
    float dn = dinv[n];
    float4* yp = reinterpret_cast<float4*>(y + (size_t)n * HID);
    #pragma unroll
    for (int q = 0; q < 4; ++q) {
        float o[4];
        #pragma unroll
        for (int ii = 0; ii < 4; ++ii) {
            int i = q * 4 + ii;
            float s = 0.f;
            #pragma unroll
            for (int j = 0; j < HID; ++j) s += W[i * HID + j] * hv[j];
            o[ii] = s * dn;
        }
        float4 v; v.x = o[0]; v.y = o[1]; v.z = o[2]; v.w = o[3];
        yp[q] = v;
    }
}

// ---------------- CSR gather: 8 lanes per node (rowptr = START now) ---------
__global__ __launch_bounds__(256) void k_gather(const unsigned* __restrict__ rowptr,
                                                const unsigned* __restrict__ deg,
                                                const unsigned* __restrict__ csr,
                                                const float* __restrict__ y,
                                                const float* __restrict__ dinv,
                                                const float* __restrict__ gcnbf,
                                                float* __restrict__ h, int N) {
    long long tid = (long long)blockIdx.x * 256 + threadIdx.x;
    if (tid >= (long long)N * 8) return;
    int n = (int)(tid >> 3), o = (int)(tid & 7);
    unsigned start = rowptr[n];
    unsigned end = start + deg[n];
    float a[16];
    #pragma unroll
    for (int j = 0; j < 16; ++j) a[j] = 0.f;
    for (unsigned k = start + o; k < end; k += 8) {
        unsigned src = csr[k];
        const float4* yp = reinterpret_cast<const float4*>(y + (size_t)src * HID);
        float4 v0 = yp[0], v1 = yp[1], v2 = yp[2], v3 = yp[3];
        a[0] += v0.x; a[1] += v0.y; a[2]  += v0.z; a[3]  += v0.w;
        a[4] += v1.x; a[5] += v1.y; a[6]  += v1.z; a[7]  += v1.w;
        a[8] += v2.x; a[9] += v2.y; a[10] += v2.z; a[11] += v2.w;
        a[12] += v3.x; a[13] += v3.y; a[14] += v3.z; a[15] += v3.w;
    }
    #pragma unroll
    for (int m = 1; m < 8; m <<= 1) {
        #pragma unroll
        for (int j = 0; j < 16; ++j) a[j] += __shfl_xor(a[j], m, 64);
    }
    if (o < 4) {
        int q = o;
        float4 self = *reinterpret_cast<const float4*>(y + (size_t)n * HID + q * 4);
        float4 r;
        if (q == 0)      { r.x = a[0];  r.y = a[1];  r.z = a[2];  r.w = a[3];  }
        else if (q == 1) { r.x = a[4];  r.y = a[5];  r.z = a[6];  r.w = a[7];  }
        else if (q == 2) { r.x = a[8];  r.y = a[9];  r.z = a[10]; r.w = a[11]; }
        else             { r.x = a[12]; r.y = a[13]; r.z = a[14]; r.w = a[15]; }
        float dn = dinv[n];
        float4 oo;
        oo.x = lrelu(fin(dn * (r.x + self.x)) + gcnbf[q*4+0]);
        oo.y = lrelu(fin(dn * (r.y + self.y)) + gcnbf[q*4+1]);
        oo.z = lrelu(fin(dn * (r.z + self.z)) + gcnbf[q*4+2]);
        oo.w = lrelu(fin(dn * (r.w + self.w)) + gcnbf[q*4+3]);
        *reinterpret_cast<float4*>(h + (size_t)n * HID + q * 4) = oo;
    }
}

// ---------------- CSR gather, final layer + heads (rowptr = START) ----------
__global__ __launch_bounds__(256) void k_gather_final(const unsigned* __restrict__ rowptr,
                                                      const unsigned* __restrict__ deg,
                                                      const unsigned* __restrict__ csr,
                                                      const float* __restrict__ y,
                                                      const float* __restrict__ dinv,
                                                      const float* __restrict__ gcnbf,
                                                      const float* __restrict__ post,
                                                      const int* __restrict__ flags,
                                                      void* __restrict__ out, int N) {
    long long tid = (long long)blockIdx.x * 256 + threadIdx.x;
    if (tid >= (long long)N * 8) return;
    int n = (int)(tid >> 3), o = (int)(tid & 7);
    unsigned start = rowptr[n];
    unsigned end = start + deg[n];
    float a[16];
    #pragma unroll
    for (int j = 0; j < 16; ++j) a[j] = 0.f;
    for (unsigned k = start + o; k < end; k += 8) {
        unsigned src = csr[k];
        const float4* yp = reinterpret_cast<const float4*>(y + (size_t)src * HID);
        float4 v0 = yp[0], v1 = yp[1], v2 = yp[2], v3 = yp[3];
        a[0] += v0.x; a[1] += v0.y; a[2]  += v0.z; a[3]  += v0.w;
        a[4] += v1.x; a[5] += v1.y; a[6]  += v1.z; a[7]  += v1.w;
        a[8] += v2.x; a[9] += v2.y; a[10] += v2.z; a[11] += v2.w;
        a[12] += v3.x; a[13] += v3.y; a[14] += v3.z; a[15] += v3.w;
    }
    #pragma unroll
    for (int m = 1; m < 8; m <<= 1) {
        #pragma unroll
        for (int j = 0; j < 16; ++j) a[j] += __shfl_xor(a[j], m, 64);
    }
    int q = o & 3;
    float s1 = 0.f, s2 = 0.f;
    float v0 = 0.f, v1 = 0.f, v2 = 0.f, v3 = 0.f;
    float dn = dinv[n];
    if (o < 4) {
        float4 self = *reinterpret_cast<const float4*>(y + (size_t)n * HID + q * 4);
        float4 r;
        if (q == 0)      { r.x = a[0];  r.y = a[1];  r.z = a[2];  r.w = a[3];  }
        else if (q == 1) { r.x = a[4];  r.y = a[5];  r.z = a[6];  r.w = a[7];  }
        else if (q == 2) { r.x = a[8];  r.y = a[9];  r.z = a[10]; r.w = a[11]; }
        else             { r.x = a[12]; r.y = a[13]; r.z = a[14]; r.w = a[15]; }
        v0 = lrelu(fin(dn * (r.x + self.x)) + gcnbf[q*4+0]);
        v1 = lrelu(fin(dn * (r.y + self.y)) + gcnbf[q*4+1]);
        v2 = lrelu(fin(dn * (r.z + self.z)) + gcnbf[q*4+2]);
        v3 = lrelu(fin(dn * (r.w + self.w)) + gcnbf[q*4+3]);
        s1 = v0 * post[q*4+0] + v1 * post[q*4+1] + v2 * post[q*4+2] + v3 * post[q*4+3];
        s2 = v0 * post[17+q*4+0] + v1 * post[17+q*4+1] + v2 * post[17+q*4+2] + v3 * post[17+q*4+3];
    }
    #pragma unroll
    for (int m = 1; m < 8; m <<= 1) {
        s1 += __shfl_xor(s1, m, 64);
        s2 += __shfl_xor(s2, m, 64);
    }
    if (o < 4) {
        if (flags[1]) {
            float* ob = (float*)out;
            if (o == 0) ob[n] = s1 + post[16];
            if (o == 1) ob[N + n] = s2 + post[33];
            float4 w; w.x = v0; w.y = v1; w.z = v2; w.w = v3;
            *reinterpret_cast<float4*>(ob + 2 * (size_t)N + (size_t)n * HID + q * 4) = w;
        } else {
            unsigned short* ob = (unsigned short*)out;
            if (o == 0) ob[n] = f2bf(s1 + post[16]);
            if (o == 1) ob[N + n] = f2bf(s2 + post[33]);
            uint2 u; u.x = pk2(v0, v1); u.y = pk2(v2, v3);
            *reinterpret_cast<uint2*>(ob + 2 * (size_t)N + (size_t)n * HID + q * 4) = u;
        }
    }
}

// ================= fallback (atomic) path kernels =================
__global__ void k_xw(const float* __restrict__ h, const float* __restrict__ W,
                     const float* __restrict__ dinv, const int* __restrict__ flags,
                     void* __restrict__ xw, float* __restrict__ hacc, int N) {
    int n = blockIdx.x * 256 + threadIdx.x;
    if (n >= N) return;
    float hv[HID];
    const float4* hp = reinterpret_cast<const float4*>(h + (size_t)n * HID);
    #pragma unroll
    for (int q = 0; q < 4; ++q) {
        float4 v = hp[q];
        hv[q*4+0] = v.x; hv[q*4+1] = v.y; hv[q*4+2] = v.z; hv[q*4+3] = v.w;
    }
    float dn = dinv[n];
    float sl = dn * dn;
    float o[HID];
    #pragma unroll
    for (int i = 0; i < HID; ++i) {
        float s = 0.f;
        #pragma unroll
        for (int j = 0; j < HID; ++j) s += W[i * HID + j] * hv[j];
        o[i] = s;
    }
    if (flags[1]) {
        float4* xp = reinterpret_cast<float4*>((float*)xw + (size_t)n * HID);
        #pragma unroll
        for (int q = 0; q < 4; ++q) {
            float4 v; v.x = o[q*4+0]; v.y = o[q*4+1]; v.z = o[q*4+2]; v.w = o[q*4+3];
            xp[q] = v;
        }
    } else {
        uint4* xp = reinterpret_cast<uint4*>((unsigned short*)xw + (size_t)n * HID);
        xp[0] = pack8(o);
        xp[1] = pack8(o + 8);
    }
    float4* ap = reinterpret_cast<float4*>(hacc + (size_t)n * HID);
    #pragma unroll
    for (int q = 0; q < 4; ++q) {
        float4 va;
        va.x = o[q*4+0]*sl; va.y = o[q*4+1]*sl; va.z = o[q*4+2]*sl; va.w = o[q*4+3]*sl;
        ap[q] = va;
    }
}

__global__ __launch_bounds__(256) void k_scatter(const int* __restrict__ ei,
                                                 const int* __restrict__ flags,
                                                 const float* __restrict__ dinv,
                                                 const void* __restrict__ xw,
                                                 float* __restrict__ hacc, int E, int N) {
    int e = blockIdx.x * 256 + threadIdx.x;
    if (e >= E) return;
    int s, d;
    if (flags[0]) { s = ei[2 * (size_t)e]; d = ei[2 * ((size_t)E + e)]; }
    else          { s = ei[e];             d = ei[(size_t)E + e]; }
    if ((unsigned)s >= (unsigned)N || (unsigned)d >= (unsigned)N) return;
    float nrm = dinv[s] * dinv[d];
    float v[HID];
    if (flags[1]) {
        const float4* xr = reinterpret_cast<const float4*>((const float*)xw + (size_t)s * HID);
        #pragma unroll
        for (int q = 0; q < 4; ++q) {
            float4 a = xr[q];
            v[q*4+0] = a.x; v[q*4+1] = a.y; v[q*4+2] = a.z; v[q*4+3] = a.w;
        }
    } else {
        const uint4* xr = reinterpret_cast<const uint4*>((const unsigned short*)xw + (size_t)s * HID);
        unpack8(xr[0], v);
        unpack8(xr[1], v + 8);
    }
    float* out = hacc + (size_t)d * HID;
    #pragma unroll
    for (int j = 0; j < HID; ++j) unsafeAtomicAdd(out + j, v[j] * nrm);
}

__global__ void k_finish(const float* __restrict__ hacc, const float* __restrict__ gcnbf,
                         float* __restrict__ h, int N) {
    int n = blockIdx.x * 256 + threadIdx.x;
    if (n >= N) return;
    const float4* ap = reinterpret_cast<const float4*>(hacc + (size_t)n * HID);
    float4* hp = reinterpret_cast<float4*>(h + (size_t)n * HID);
    #pragma unroll
    for (int q = 0; q < 4; ++q) {
        float4 a = ap[q];
        float4 o;
        o.x = lrelu(fin(a.x) + gcnbf[q*4+0]);
        o.y = lrelu(fin(a.y) + gcnbf[q*4+1]);
        o.z = lrelu(fin(a.z) + gcnbf[q*4+2]);
        o.w = lrelu(fin(a.w) + gcnbf[q*4+3]);
        hp[q] = o;
    }
}

__global__ void k_final(const float* __restrict__ hacc, const float* __restrict__ gcnbf,
                        const float* __restrict__ post, const int* __restrict__ flags,
                        void* __restrict__ out, int N) {
    int n = blockIdx.x * 256 + threadIdx.x;
    if (n >= N) return;
    float v[HID];
    const float4* ap = reinterpret_cast<const float4*>(hacc + (size_t)n * HID);
    #pragma unroll
    for (int q = 0; q < 4; ++q) {
        float4 a = ap[q];
        v[q*4+0] = lrelu(fin(a.x) + gcnbf[q*4+0]);
        v[q*4+1] = lrelu(fin(a.y) + gcnbf[q*4+1]);
        v[q*4+2] = lrelu(fin(a.z) + gcnbf[q*4+2]);
        v[q*4+3] = lrelu(fin(a.w) + gcnbf[q*4+3]);
    }
    float o = post[16], an = post[33];
    #pragma unroll
    for (int j = 0; j < HID; ++j) {
        o += v[j] * post[j];
        an += v[j] * post[17 + j];
    }
    if (flags[1]) {
        float* ob = (float*)out;
        ob[n] = o;
        ob[N + n] = an;
        float* hr = ob + 2 * (size_t)N + (size_t)n * HID;
        #pragma unroll
        for (int j = 0; j < HID; ++j) hr[j] = v[j];
    } else {
        unsigned short* ob = (unsigned short*)out;
        ob[n] = f2bf(o);
        ob[N + n] = f2bf(an);
        uint4* hr = reinterpret_cast<uint4*>(ob + 2 * (size_t)N + (size_t)n * HID);
        hr[0] = pack8(v);
        hr[1] = pack8(v + 8);
    }
}

extern "C" void kernel_launch(void* const* d_in, const int* in_sizes, int n_in,
                              void* d_out, int out_size, void* d_ws, size_t ws_size,
                              hipStream_t stream) {
    const void* x    = d_in[0];
    const int*  ei   = (const int*)d_in[1];
    const void* p1W  = d_in[2];
    const void* p1b  = d_in[3];
    const void* p2W  = d_in[4];
    const void* p2b  = d_in[5];
    const void* bih  = d_in[6];
    const void* bhh  = d_in[7];
    const void* wtW  = d_in[8];
    const void* wtb  = d_in[9];
    const void* gcnb = d_in[10];
    const void* po1W = d_in[11];
    const void* po1b = d_in[12];
    const void* poaW = d_in[13];
    const void* poab = d_in[14];

    const int N = in_sizes[0] / IN_DIM;   // 100000
    const int E = in_sizes[1] / 2;        // 3200000

    float* ws = (float*)d_ws;
    float* w1q   = ws + OFF_W1F;
    float* b1f   = ws + OFF_B1F;
    float* w2t   = ws + OFF_W2T;
    float* b2f   = ws + OFF_B2F;
    float* hw    = ws + OFF_HW;
    float* gcnbf = ws + OFF_GCNB;
    float* post  = ws + OFF_POST;
    int*   flags = (int*)(ws + OFF_FLAGS);
    unsigned* bsum = (unsigned*)(ws + OFF_BSUM);
    unsigned* bpre = (unsigned*)(ws + OFF_BPRE);

    const int nb_nodes = (N + 255) / 256;
    const int nb_edges = (E + 255) / 256;
    const int nb_n8    = (int)(((long long)N * 8 + 255) / 256);
    const int nb_pre   = (N + 63) / 64;
    const int NB       = (N + 1023) / 1024;

    size_t req_csr = ((size_t)OFF_A0 + 35 * (size_t)N + (size_t)E + 64) * 4;
    size_t req_fb  = ((size_t)OFF_A0 + 33 * (size_t)N + 64) * 4;

    if (ws_size >= req_csr && NB <= 128) {
        // ================= CSR (pull) path =================
        unsigned* deg    = (unsigned*)(ws + OFF_A0);
        unsigned* rowptr = deg + N;
        float*    dinv   = (float*)(rowptr + N);
        unsigned* csr    = (unsigned*)(dinv + N);
        float*    y      = (float*)(csr + E);
        float*    h      = y + (size_t)N * HID;

        // degree replicas + replica cursors overlay y (16N uints = 16N floats);
        // both dead before k_xw_y writes y
        unsigned* degr       = (unsigned*)y;
        unsigned* rowptr_rep = degr + (size_t)NRANGE * N;

        hipMemsetAsync(degr, 0, (size_t)NRANGE * N * 4, stream);
        k_detect<<<1, 64, 0, stream>>>((const unsigned short*)x, ei, flags);
        k_prep_small<<<1, 256, 0, stream>>>(bih, bhh, wtW, wtb, po1W, po1b, poaW, poab,
                                            flags, hw, post);
        k_convert<<<128, 256, 0, stream>>>(p1W, p1b, p2W, p2b, gcnb, flags,
                                           w1q, b1f, w2t, b2f, gcnbf);
        k_deg_rep<<<nb_edges, 256, 0, stream>>>(ei, flags, degr, E, N);
        k_scan_block<<<NB, 1024, 0, stream>>>(degr, deg, bsum, N);
        k_scan_top<<<1, 128, 0, stream>>>(bsum, bpre, NB);
        k_scan_final<<<NB, 1024, 0, stream>>>(deg, bpre, rowptr, dinv, N);
        k_rowrep<<<nb_nodes, 256, 0, stream>>>(rowptr, degr, rowptr_rep, N);
        k_fill_rep<<<nb_edges, 256, 0, stream>>>(ei, flags, rowptr_rep, csr, E, N);
        k_pre_lds<<<nb_pre, 512, 0, stream>>>(x, w1q, b1f, w2t, b2f, flags, h, N);

        k_xw_y<<<nb_nodes, 256, 0, stream>>>(h, hw + 0, dinv, y, N);
        k_gather<<<nb_n8, 256, 0, stream>>>(rowptr, deg, csr, y, dinv, gcnbf + 0, h, N);
        k_xw_y<<<nb_nodes, 256, 0, stream>>>(h, hw + 256, dinv, y, N);
        k_gather_final<<<nb_n8, 256, 0, stream>>>(rowptr, deg, csr, y, dinv, gcnbf + 16,
                                                  post, flags, d_out, N);
    } else if (ws_size >= req_fb) {
        // ================= fallback (atomic) path =================
        float* degdinv = ws + OFF_A0;
        float* hacc    = degdinv + N;
        float* h       = hacc + (size_t)N * HID;
        void*  xw      = d_out;

        hipMemsetAsync(degdinv, 0, (size_t)N * 4, stream);
        k_detect<<<1, 64, 0, stream>>>((const unsigned short*)x, ei, flags);
        k_prep_small<<<1, 256, 0, stream>>>(bih, bhh, wtW, wtb, po1W, po1b, poaW, poab,
                                            flags, hw, post);
        k_convert<<<128, 256, 0, stream>>>(p1W, p1b, p2W, p2b, gcnb, flags,
                                           w1q, b1f, w2t, b2f, gcnbf);
        k_deg<<<nb_edges * NRANGE, 256, 0, stream>>>(ei, flags, (unsigned*)degdinv, E, N);
        k_dinv<<<nb_nodes, 256, 0, stream>>>(degdinv, N);
        k_pre_lds<<<nb_pre, 512, 0, stream>>>(x, w1q, b1f, w2t, b2f, flags, h, N);
        for (int l = 0; l < 2; ++l) {
            k_xw<<<nb_nodes, 256, 0, stream>>>(h, hw + l * 256, degdinv, flags, xw, hacc, N);
            k_scatter<<<nb_edges, 256, 0, stream>>>(ei, flags, degdinv, xw, hacc, E, N);
            if (l == 0) k_finish<<<nb_nodes, 256, 0, stream>>>(hacc, gcnbf + 0, h, N);
            else        k_final<<<nb_nodes, 256, 0, stream>>>(hacc, gcnbf + 16, post, flags, d_out, N);
        }
    } else {
        float f = 256.0f + (float)(ws_size >> 20);
        unsigned uv; __builtin_memcpy(&uv, &f, 4);
        int words = out_size / 2;
        k_sentinel<<<(words + 255) / 256, 256, 0, stream>>>((unsigned*)d_out, words, uv);
    }
}

// Round 17
// 615.668 us; speedup vs baseline: 1.2179x; 1.2179x over previous
//
#include <hip/hip_runtime.h>
#include <hip/hip_bf16.h>
#include <math.h>

#define IN_DIM 128
#define PRE_HID 256
#define HID 16
#define NRANGE 8

__device__ __forceinline__ float lrelu(float v) { return v > 0.f ? v : 0.01f * v; }
__device__ __forceinline__ float fin(float v) { return (v == v && fabsf(v) < 1e30f) ? v : 0.f; }

__device__ __forceinline__ float ldp(const void* p, size_t i, int f32) {
    if (f32) return ((const float*)p)[i];
    unsigned u = ((const unsigned short*)p)[i];
    return __uint_as_float(u << 16);
}
__device__ __forceinline__ unsigned short f2bf(float f) {
    union { __hip_bfloat16 b; unsigned short u; } cv;
    cv.b = __float2bfloat16(f);
    return cv.u;
}
__device__ __forceinline__ void unpack8(uint4 u, float* o) {
    o[0] = __uint_as_float(u.x << 16); o[1] = __uint_as_float(u.x & 0xFFFF0000u);
    o[2] = __uint_as_float(u.y << 16); o[3] = __uint_as_float(u.y & 0xFFFF0000u);
    o[4] = __uint_as_float(u.z << 16); o[5] = __uint_as_float(u.z & 0xFFFF0000u);
    o[6] = __uint_as_float(u.w << 16); o[7] = __uint_as_float(u.w & 0xFFFF0000u);
}
__device__ __forceinline__ unsigned pk2(float a, float b) {
    return (unsigned)f2bf(a) | ((unsigned)f2bf(b) << 16);
}
__device__ __forceinline__ uint4 pack8(const float* v) {
    uint4 u;
    u.x = pk2(v[0], v[1]); u.y = pk2(v[2], v[3]);
    u.z = pk2(v[4], v[5]); u.w = pk2(v[6], v[7]);
    return u;
}

// ---- fixed small-param region (float offsets)
#define OFF_W1F   0          // fp32 [32768]  (w1q: k-major [32][256][4])
#define OFF_B1F   32768      // fp32 [256]
#define OFF_W2T   33024      // fp32 [4096]   (w2t: [256][16])
#define OFF_B2F   37120      // fp32 [16]
#define OFF_HW    37136      // fp32 [2][256]
#define OFF_GCNB  37648      // fp32 [2][16]
#define OFF_POST  37680      // fp32 [34] (+pad)
#define OFF_FLAGS 37720      // int [2]: [0]=int64 edges, [1]=fp32 floats
#define OFF_BSUM  37760      // uint [128]
#define OFF_BPRE  37888      // uint [128]
#define OFF_A0    38016      // N-dependent regions start here

// ---------------- dtype detection ----------------
__global__ void k_detect(const unsigned short* __restrict__ xu,
                         const int* __restrict__ ei32, int* __restrict__ flags) {
    if (threadIdx.x == 0 && blockIdx.x == 0) {
        int band = 0;
        for (int k = 0; k < 128; ++k) {
            unsigned e = (xu[2 * k] >> 7) & 0xFF;
            if (e >= 100 && e <= 140) band++;
        }
        flags[1] = (band < 96) ? 1 : 0;  // low in-band => fp32 data
        int any = 0;
        for (int k = 0; k < 64; ++k) any |= ei32[2 * k + 1];
        flags[0] = (any == 0) ? 1 : 0;   // all-zero odd slots => int64
    }
}

__global__ void k_sentinel(unsigned* __restrict__ out, int words, unsigned val) {
    int i = blockIdx.x * 256 + threadIdx.x;
    if (i < words) out[i] = val;
}

// ---------------- small params ----------------
__global__ void k_prep_small(const void* __restrict__ bih, const void* __restrict__ bhh,
                             const void* __restrict__ wtW, const void* __restrict__ wtb,
                             const void* __restrict__ p1W, const void* __restrict__ p1b,
                             const void* __restrict__ paW, const void* __restrict__ pab,
                             const int* __restrict__ flags,
                             float* __restrict__ hw, float* __restrict__ post) {
    int f32 = flags[1];
    __shared__ float mem[2][16];
    int t = threadIdx.x;
    if (t < 32) {
        int l = t >> 4, j = t & 15;
        float bi0 = ldp(bih, l * 48 + j, f32),      bh0 = ldp(bhh, l * 48 + j, f32);
        float bi1 = ldp(bih, l * 48 + 16 + j, f32), bh1 = ldp(bhh, l * 48 + 16 + j, f32);
        float bi2 = ldp(bih, l * 48 + 32 + j, f32), bh2 = ldp(bhh, l * 48 + 32 + j, f32);
        float r = 1.f / (1.f + expf(-(bi0 + bh0)));
        float z = 1.f / (1.f + expf(-(bi1 + bh1)));
        float nn = tanhf(bi2 + r * bh2);
        mem[l][j] = (1.f - z) * nn;
    }
    __syncthreads();
    for (int l = 0; l < 2; ++l) {
        float acc = ldp(wtb, l * 256 + t, f32);
        #pragma unroll
        for (int m = 0; m < 16; ++m)
            acc += ldp(wtW, l * 4096 + t * 16 + m, f32) * mem[l][m];
        hw[l * 256 + t] = acc;
    }
    if (t < 16) {
        post[t]      = ldp(p1W, t, f32) + ldp(p1W, 16 + t, f32);
        post[17 + t] = ldp(paW, t, f32);
    }
    if (t == 0) {
        post[16] = ldp(p1b, 0, f32) + ldp(p1b, 1, f32);
        post[33] = ldp(pab, 0, f32);
    }
}

__global__ void k_convert(const void* __restrict__ p1W, const void* __restrict__ p1b,
                          const void* __restrict__ p2W, const void* __restrict__ p2b,
                          const void* __restrict__ gcnb, const int* __restrict__ flags,
                          float* __restrict__ w1q, float* __restrict__ b1f,
                          float* __restrict__ w2t, float* __restrict__ b2f,
                          float* __restrict__ gcnbf) {
    int f32 = flags[1];
    int i = blockIdx.x * 256 + threadIdx.x;
    // w1q[kq][r][i2] = W1[r][4*kq + i2]  (k-major float4 rows for grouped loads)
    if (i < 32768) {
        int i2 = i & 3, r = (i >> 2) & 255, kq = i >> 10;
        w1q[i] = ldp(p1W, (size_t)r * 128 + kq * 4 + i2, f32);
    }
    if (i < 256)   b1f[i] = ldp(p1b, i, f32);
    if (i < 4096)  { int r = i >> 4, j = i & 15; w2t[i] = ldp(p2W, j * 256 + r, f32); }
    if (i < 16)    b2f[i] = ldp(p2b, i, f32);
    if (i < 32)    gcnbf[i] = ldp(gcnb, i, f32);
}

// ---------------- degree: ONE edge scan, 8-way replicated histogram ---------
// (R15 win, kept: -8us vs ranged 8-scan. Atomics on the small 400KB-per-
// replica histogram ARE locality-tolerant; the R16 lesson is that csr WRITES
// are not — see k_fill.)
__global__ void k_deg_rep(const int* __restrict__ ei, const int* __restrict__ flags,
                          unsigned* __restrict__ degr, int E, int N) {
    int e = blockIdx.x * 256 + threadIdx.x;
    if (e >= E) return;
    int rep = blockIdx.x & (NRANGE - 1);
    int d = flags[0] ? ei[2 * ((size_t)E + e)] : ei[(size_t)E + e];
    if ((unsigned)d < (unsigned)N) atomicAdd(&degr[(size_t)rep * N + d], 1u);
}

// legacy ranged version (fallback path only)
__global__ void k_deg(const int* __restrict__ ei, const int* __restrict__ flags,
                      unsigned* __restrict__ deg, int E, int N) {
    int rid = blockIdx.x & (NRANGE - 1);
    int e = (blockIdx.x >> 3) * 256 + threadIdx.x;
    if (e >= E) return;
    int R = (N + NRANGE - 1) / NRANGE;
    int lo = rid * R;
    int hi = lo + R; if (hi > N) hi = N;
    int d = flags[0] ? ei[2 * ((size_t)E + e)] : ei[(size_t)E + e];
    if (d >= lo && d < hi) atomicAdd(&deg[d], 1u);
}

__global__ void k_dinv(float* __restrict__ degdinv, int N) {
    int n = blockIdx.x * 256 + threadIdx.x;
    if (n >= N) return;
    unsigned dg = ((unsigned*)degdinv)[n];
    degdinv[n] = 1.f / sqrtf((float)dg + 1.f);
}

// ---------------- prefix scan ----------------
// scan_block sums the 8 degree replicas and materializes deg[i]
__global__ __launch_bounds__(1024) void k_scan_block(const unsigned* __restrict__ degr,
                                                     unsigned* __restrict__ deg,
                                                     unsigned* __restrict__ bsum, int N) {
    __shared__ unsigned s[1024];
    int t = threadIdx.x;
    int i = blockIdx.x * 1024 + t;
    unsigned v = 0u;
    if (i < N) {
        #pragma unroll
        for (int r = 0; r < NRANGE; ++r) v += degr[(size_t)r * N + i];
        deg[i] = v;
    }
    s[t] = v;
    __syncthreads();
    for (int off = 512; off > 0; off >>= 1) {
        if (t < off) s[t] += s[t + off];
        __syncthreads();
    }
    if (t == 0) bsum[blockIdx.x] = s[0];
}

__global__ __launch_bounds__(128) void k_scan_top(unsigned* __restrict__ bsum,
                                                  unsigned* __restrict__ bpre, int NB) {
    __shared__ unsigned s[128];
    int t = threadIdx.x;
    unsigned v = (t < NB) ? bsum[t] : 0u;
    s[t] = v;
    __syncthreads();
    for (int off = 1; off < 128; off <<= 1) {
        unsigned a = (t >= off) ? s[t - off] : 0u;
        __syncthreads();
        s[t] += a;
        __syncthreads();
    }
    if (t < NB) bpre[t] = s[t] - v;
}

// scan_final emits rowptr (exclusive prefix = segment start) and dinv
__global__ __launch_bounds__(1024) void k_scan_final(const unsigned* __restrict__ deg,
                                                     const unsigned* __restrict__ bpre,
                                                     unsigned* __restrict__ rowptr,
                                                     float* __restrict__ dinv, int N) {
    __shared__ unsigned s[1024];
    int t = threadIdx.x;
    int i = blockIdx.x * 1024 + t;
    unsigned v = (i < N) ? deg[i] : 0u;
    s[t] = v;
    __syncthreads();
    for (int off = 1; off < 1024; off <<= 1) {
        unsigned a = (t >= off) ? s[t - off] : 0u;
        __syncthreads();
        s[t] += a;
        __syncthreads();
    }
    if (i < N) {
        rowptr[i] = bpre[blockIdx.x] + s[t] - v;
        dinv[i] = 1.f / sqrtf((float)v + 1.f);
    }
}

// ---------------- CSR fill: range-partitioned scatter (R7/R15 form) ---------
// R16 lesson: the ranged scheme's benefit is csr WRITE locality — rowptr is
// monotonic, so range [lo,hi) maps to a CONTIGUOUS ~1.6MB csr slice that
// stays L2-resident (lines fill before eviction). The single-pass replica
// variant scattered writes over all 12.8MB -> 190MB writeback, 2.6x slower.
// rowptr is consumed as cursor (ends at segment END); gathers use end-deg.
__global__ void k_fill(const int* __restrict__ ei, const int* __restrict__ flags,
                       unsigned* __restrict__ rowptr, unsigned* __restrict__ csr,
                       int E, int N) {
    int rid = blockIdx.x & (NRANGE - 1);
    int e = (blockIdx.x >> 3) * 256 + threadIdx.x;
    if (e >= E) return;
    int R = (N + NRANGE - 1) / NRANGE;
    int lo = rid * R;
    int hi = lo + R; if (hi > N) hi = N;
    int d = flags[0] ? ei[2 * ((size_t)E + e)] : ei[(size_t)E + e];
    if (d < lo || d >= hi) return;
    int s = flags[0] ? ei[2 * (size_t)e] : ei[e];
    if ((unsigned)s >= (unsigned)N) s = d;
    unsigned pos = atomicAdd(&rowptr[d], 1u);
    csr[pos] = (unsigned)s;
}

// ---------------- preprocess: 8-wave cooperative LDS tile (R9 form) ----------
__global__ __launch_bounds__(512) void k_pre_lds(const void* __restrict__ x,
                                                 const float* __restrict__ w1q,
                                                 const float* __restrict__ b1f,
                                                 const float* __restrict__ w2t,
                                                 const float* __restrict__ b2f,
                                                 const int* __restrict__ flags,
                                                 float* __restrict__ h, int N) {
    __shared__ __align__(16) float smem[8320];      // 32.5 KB: xs (65-pad), red overlay
    const int t = threadIdx.x;
    const int l = t & 63;
    const int wu = __builtin_amdgcn_readfirstlane(t >> 6);  // 0..7, wave-uniform
    const int nb0 = blockIdx.x * 64;
    const int f32 = flags[1];

    // ---- stage x[nb0..nb0+63][:] -> xs[kq][node][4]  (smem[(kq*65+n)*4 + i])
    {
        int n = t >> 3;                 // staged node 0..63
        int gn = nb0 + n; if (gn >= N) gn = N - 1;
        if (f32) {
            int c0 = (t & 7) * 4;       // this thread's 4 k-quads
            const float4* gx = reinterpret_cast<const float4*>((const float*)x + (size_t)gn * IN_DIM);
            #pragma unroll
            for (int j = 0; j < 4; ++j) {
                float4 v = gx[c0 + j];
                *reinterpret_cast<float4*>(&smem[((c0 + j) * 65 + n) * 4]) = v;
            }
        } else {
            const uint4* gx = reinterpret_cast<const uint4*>((const unsigned short*)x + (size_t)gn * IN_DIM);
            #pragma unroll
            for (int jj = 0; jj < 2; ++jj) {
                int j = (t & 7) * 2 + jj;       // uint4 index 0..15
                float o[8];
                unpack8(gx[j], o);
                float4 v0, v1;
                v0.x = o[0]; v0.y = o[1]; v0.z = o[2]; v0.w = o[3];
                v1.x = o[4]; v1.y = o[5]; v1.z = o[6]; v1.w = o[7];
                *reinterpret_cast<float4*>(&smem[((j * 2) * 65 + n) * 4]) = v0;
                *reinterpret_cast<float4*>(&smem[((j * 2 + 1) * 65 + n) * 4]) = v1;
            }
        }
    }
    __syncthreads();

    // ---- layer 1: wave's 32 rows, kq-outer so one xv read feeds 128 FMAs
    const int rr = wu * 32;                       // wave-uniform row base
    float s[32];
    #pragma unroll
    for (int r = 0; r < 32; ++r) s[r] = b1f[rr + r];

    #pragma unroll 1
    for (int kq = 0; kq < 32; ++kq) {
        float4 xv = *reinterpret_cast<const float4*>(&smem[(kq * 65 + l) * 4]);
        const float4* wq = reinterpret_cast<const float4*>(w1q + ((size_t)kq * 256 + rr) * 4);
        {
            float4 w[16];
            #pragma unroll
            for (int r = 0; r < 16; ++r) w[r] = wq[r];       // grouped s_loads
            #pragma unroll
            for (int r = 0; r < 16; ++r)
                s[r] += w[r].x * xv.x + w[r].y * xv.y + w[r].z * xv.z + w[r].w * xv.w;
        }
        {
            float4 w[16];
            #pragma unroll
            for (int r = 0; r < 16; ++r) w[r] = wq[16 + r];
            #pragma unroll
            for (int r = 0; r < 16; ++r)
                s[16 + r] += w[r].x * xv.x + w[r].y * xv.y + w[r].z * xv.z + w[r].w * xv.w;
        }
    }

    // ---- layer 2 fold over this wave's 32 rows
    float acc2[16];
    #pragma unroll
    for (int j = 0; j < 16; ++j) acc2[j] = 0.f;
    #pragma unroll
    for (int r = 0; r < 32; ++r) {
        float tv = lrelu(s[r]);
        const float* w2r = w2t + (size_t)(rr + r) * HID;     // wave-uniform
        #pragma unroll
        for (int j = 0; j < 16; ++j) acc2[j] += w2r[j] * tv;
    }
    __syncthreads();                  // xs dead from here; red overlays it

    // ---- cross-wave reduction via overlaid red[j][wave][node] (conflict-free)
    #pragma unroll
    for (int j = 0; j < 16; ++j) smem[(j * 8 + wu) * 64 + l] = acc2[j];
    __syncthreads();

    // ---- reduce 8 wave partials, bias + lrelu, store h[64][16] (threads 0..255)
    if (t < 256) {
        int n = t & 63, jq = t >> 6;
        int gn = nb0 + n;
        if (gn < N) {
            float o[4];
            #pragma unroll
            for (int i = 0; i < 4; ++i) {
                int j = jq * 4 + i;
                float v = 0.f;
                #pragma unroll
                for (int w = 0; w < 8; ++w) v += smem[(j * 8 + w) * 64 + n];
                o[i] = lrelu(v + b2f[j]);
            }
            float4 v; v.x = o[0]; v.y = o[1]; v.z = o[2]; v.w = o[3];
            *reinterpret_cast<float4*>(h + (size_t)gn * HID + jq * 4) = v;
        }
    }
}

// ---------------- CSR path: y = (h @ W^T) * dinv[n] ----------------
__global__ void k_xw_y(const float* __restrict__ h, const float* __restrict__ W,
                       const float* __restrict__ dinv, float* __restrict__ y, int N) {
    int n = blockIdx.x * 256 + threadIdx.x;
    if (n >= N) return;
    float hv[HID];
    const float4* hp = reinterpret_cast<const float4*>(h + (size_t)n * HID);
    #pragma unroll
    for (int q = 0; q < 4; ++q) {
        float4 v = hp[q];
        hv[q*4+0] = v.x; hv[q*4+1] = v.y; hv[q*4+2] = v.z; hv[q*4+3] = v.w;
    }
    float dn = dinv[n];
    float4* yp = reinterpret_cast<float4*>(y + (size_t)n * HID);
    #pragma unroll
    for (int q = 0; q < 4; ++q) {
        float o[4];
        #pragma unroll
        for (int ii = 0; ii < 4; ++ii) {
            int i = q * 4 + ii;
            float s = 0.f;
            #pragma unroll
            for (int j = 0; j < HID; ++j) s += W[i * HID + j] * hv[j];
            o[ii] = s * dn;
        }
        float4 v; v.x = o[0]; v.y = o[1]; v.z = o[2]; v.w = o[3];
        yp[q] = v;
    }
}

// ---------------- CSR gather: 8 lanes per node (rowptr = segment END) -------
__global__ __launch_bounds__(256) void k_gather(const unsigned* __restrict__ rowptr,
                                                const unsigned* __restrict__ deg,
                                                const unsigned* __restrict__ csr,
                                                const float* __restrict__ y,
                                                const float* __restrict__ dinv,
                                                const float* __restrict__ gcnbf,
                                                float* __restrict__ h, int N) {
    long long tid = (long long)blockIdx.x * 256 + threadIdx.x;
    if (tid >= (long long)N * 8) return;
    int n = (int)(tid >> 3), o = (int)(tid & 7);
    unsigned end = rowptr[n];
    unsigned start = end - deg[n];
    float a[16];
    #pragma unroll
    for (int j = 0; j < 16; ++j) a[j] = 0.f;
    for (unsigned k = start + o; k < end; k += 8) {
        unsigned src = csr[k];
        const float4* yp = reinterpret_cast<const float4*>(y + (size_t)src * HID);
        float4 v0 = yp[0], v1 = yp[1], v2 = yp[2], v3 = yp[3];
        a[0] += v0.x; a[1] += v0.y; a[2]  += v0.z; a[3]  += v0.w;
        a[4] += v1.x; a[5] += v1.y; a[6]  += v1.z; a[7]  += v1.w;
        a[8] += v2.x; a[9] += v2.y; a[10] += v2.z; a[11] += v2.w;
        a[12] += v3.x; a[13] += v3.y; a[14] += v3.z; a[15] += v3.w;
    }
    #pragma unroll
    for (int m = 1; m < 8; m <<= 1) {
        #pragma unroll
        for (int j = 0; j < 16; ++j) a[j] += __shfl_xor(a[j], m, 64);
    }
    if (o < 4) {
        int q = o;
        float4 self = *reinterpret_cast<const float4*>(y + (size_t)n * HID + q * 4);
        float4 r;
        if (q == 0)      { r.x = a[0];  r.y = a[1];  r.z = a[2];  r.w = a[3];  }
        else if (q == 1) { r.x = a[4];  r.y = a[5];  r.z = a[6];  r.w = a[7];  }
        else if (q == 2) { r.x = a[8];  r.y = a[9];  r.z = a[10]; r.w = a[11]; }
        else             { r.x = a[12]; r.y = a[13]; r.z = a[14]; r.w = a[15]; }
        float dn = dinv[n];
        float4 oo;
        oo.x = lrelu(fin(dn * (r.x + self.x)) + gcnbf[q*4+0]);
        oo.y = lrelu(fin(dn * (r.y + self.y)) + gcnbf[q*4+1]);
        oo.z = lrelu(fin(dn * (r.z + self.z)) + gcnbf[q*4+2]);
        oo.w = lrelu(fin(dn * (r.w + self.w)) + gcnbf[q*4+3]);
        *reinterpret_cast<float4*>(h + (size_t)n * HID + q * 4) = oo;
    }
}

// ---------------- CSR gather, final layer + heads (rowptr = END) ------------
__global__ __launch_bounds__(256) void k_gather_final(const unsigned* __restrict__ rowptr,
                                                      const unsigned* __restrict__ deg,
                                                      const unsigned* __restrict__ csr,
                                                      const float* __restrict__ y,
                                                      const float* __restrict__ dinv,
                                                      const float* __restrict__ gcnbf,
                                                      const float* __restrict__ post,
                                                      const int* __restrict__ flags,
                                                      void* __restrict__ out, int N) {
    long long tid = (long long)blockIdx.x * 256 + threadIdx.x;
    if (tid >= (long long)N * 8) return;
    int n = (int)(tid >> 3), o = (int)(tid & 7);
    unsigned end = rowptr[n];
    unsigned start = end - deg[n];
    float a[16];
    #pragma unroll
    for (int j = 0; j < 16; ++j) a[j] = 0.f;
    for (unsigned k = start + o; k < end; k += 8) {
        unsigned src = csr[k];
        const float4* yp = reinterpret_cast<const float4*>(y + (size_t)src * HID);
        float4 v0 = yp[0], v1 = yp[1], v2 = yp[2], v3 = yp[3];
        a[0] += v0.x; a[1] += v0.y; a[2]  += v0.z; a[3]  += v0.w;
        a[4] += v1.x; a[5] += v1.y; a[6]  += v1.z; a[7]  += v1.w;
        a[8] += v2.x; a[9] += v2.y; a[10] += v2.z; a[11] += v2.w;
        a[12] += v3.x; a[13] += v3.y; a[14] += v3.z; a[15] += v3.w;
    }
    #pragma unroll
    for (int m = 1; m < 8; m <<= 1) {
        #pragma unroll
        for (int j = 0; j < 16; ++j) a[j] += __shfl_xor(a[j], m, 64);
    }
    int q = o & 3;
    float s1 = 0.f, s2 = 0.f;
    float v0 = 0.f, v1 = 0.f, v2 = 0.f, v3 = 0.f;
    float dn = dinv[n];
    if (o < 4) {
        float4 self = *reinterpret_cast<const float4*>(y + (size_t)n * HID + q * 4);
        float4 r;
        if (q == 0)      { r.x = a[0];  r.y = a[1];  r.z = a[2];  r.w = a[3];  }
        else if (q == 1) { r.x = a[4];  r.y = a[5];  r.z = a[6];  r.w = a[7];  }
        else if (q == 2) { r.x = a[8];  r.y = a[9];  r.z = a[10]; r.w = a[11]; }
        else             { r.x = a[12]; r.y = a[13]; r.z = a[14]; r.w = a[15]; }
        v0 = lrelu(fin(dn * (r.x + self.x)) + gcnbf[q*4+0]);
        v1 = lrelu(fin(dn * (r.y + self.y)) + gcnbf[q*4+1]);
        v2 = lrelu(fin(dn * (r.z + self.z)) + gcnbf[q*4+2]);
        v3 = lrelu(fin(dn * (r.w + self.w)) + gcnbf[q*4+3]);
        s1 = v0 * post[q*4+0] + v1 * post[q*4+1] + v2 * post[q*4+2] + v3 * post[q*4+3];
        s2 = v0 * post[17+q*4+0] + v1 * post[17+q*4+1] + v2 * post[17+q*4+2] + v3 * post[17+q*4+3];
    }
    #pragma unroll
    for (int m = 1; m < 8; m <<= 1) {
        s1 += __shfl_xor(s1, m, 64);
        s2 += __shfl_xor(s2, m, 64);
    }
    if (o < 4) {
        if (flags[1]) {
            float* ob = (float*)out;
            if (o == 0) ob[n] = s1 + post[16];
            if (o == 1) ob[N + n] = s2 + post[33];
            float4 w; w.x = v0; w.y = v1; w.z = v2; w.w = v3;
            *reinterpret_cast<float4*>(ob + 2 * (size_t)N + (size_t)n * HID + q * 4) = w;
        } else {
            unsigned short* ob = (unsigned short*)out;
            if (o == 0) ob[n] = f2bf(s1 + post[16]);
            if (o == 1) ob[N + n] = f2bf(s2 + post[33]);
            uint2 u; u.x = pk2(v0, v1); u.y = pk2(v2, v3);
            *reinterpret_cast<uint2*>(ob + 2 * (size_t)N + (size_t)n * HID + q * 4) = u;
        }
    }
}

// ================= fallback (atomic) path kernels =================
__global__ void k_xw(const float* __restrict__ h, const float* __restrict__ W,
                     const float* __restrict__ dinv, const int* __restrict__ flags,
                     void* __restrict__ xw, float* __restrict__ hacc, int N) {
    int n = blockIdx.x * 256 + threadIdx.x;
    if (n >= N) return;
    float hv[HID];
    const float4* hp = reinterpret_cast<const float4*>(h + (size_t)n * HID);
    #pragma unroll
    for (int q = 0; q < 4; ++q) {
        float4 v = hp[q];
        hv[q*4+0] = v.x; hv[q*4+1] = v.y; hv[q*4+2] = v.z; hv[q*4+3] = v.w;
    }
    float dn = dinv[n];
    float sl = dn * dn;
    float o[HID];
    #pragma unroll
    for (int i = 0; i < HID; ++i) {
        float s = 0.f;
        #pragma unroll
        for (int j = 0; j < HID; ++j) s += W[i * HID + j] * hv[j];
        o[i] = s;
    }
    if (flags[1]) {
        float4* xp = reinterpret_cast<float4*>((float*)xw + (size_t)n * HID);
        #pragma unroll
        for (int q = 0; q < 4; ++q) {
            float4 v; v.x = o[q*4+0]; v.y = o[q*4+1]; v.z = o[q*4+2]; v.w = o[q*4+3];
            xp[q] = v;
        }
    } else {
        uint4* xp = reinterpret_cast<uint4*>((unsigned short*)xw + (size_t)n * HID);
        xp[0] = pack8(o);
        xp[1] = pack8(o + 8);
    }
    float4* ap = reinterpret_cast<float4*>(hacc + (size_t)n * HID);
    #pragma unroll
    for (int q = 0; q < 4; ++q) {
        float4 va;
        va.x = o[q*4+0]*sl; va.y = o[q*4+1]*sl; va.z = o[q*4+2]*sl; va.w = o[q*4+3]*sl;
        ap[q] = va;
    }
}

__global__ __launch_bounds__(256) void k_scatter(const int* __restrict__ ei,
                                                 const int* __restrict__ flags,
                                                 const float* __restrict__ dinv,
                                                 const void* __restrict__ xw,
                                                 float* __restrict__ hacc, int E, int N) {
    int e = blockIdx.x * 256 + threadIdx.x;
    if (e >= E) return;
    int s, d;
    if (flags[0]) { s = ei[2 * (size_t)e]; d = ei[2 * ((size_t)E + e)]; }
    else          { s = ei[e];             d = ei[(size_t)E + e]; }
    if ((unsigned)s >= (unsigned)N || (unsigned)d >= (unsigned)N) return;
    float nrm = dinv[s] * dinv[d];
    float v[HID];
    if (flags[1]) {
        const float4* xr = reinterpret_cast<const float4*>((const float*)xw + (size_t)s * HID);
        #pragma unroll
        for (int q = 0; q < 4; ++q) {
            float4 a = xr[q];
            v[q*4+0] = a.x; v[q*4+1] = a.y; v[q*4+2] = a.z; v[q*4+3] = a.w;
        }
    } else {
        const uint4* xr = reinterpret_cast<const uint4*>((const unsigned short*)xw + (size_t)s * HID);
        unpack8(xr[0], v);
        unpack8(xr[1], v + 8);
    }
    float* out = hacc + (size_t)d * HID;
    #pragma unroll
    for (int j = 0; j < HID; ++j) unsafeAtomicAdd(out + j, v[j] * nrm);
}

__global__ void k_finish(const float* __restrict__ hacc, const float* __restrict__ gcnbf,
                         float* __restrict__ h, int N) {
    int n = blockIdx.x * 256 + threadIdx.x;
    if (n >= N) return;
    const float4* ap = reinterpret_cast<const float4*>(hacc + (size_t)n * HID);
    float4* hp = reinterpret_cast<float4*>(h + (size_t)n * HID);
    #pragma unroll
    for (int q = 0; q < 4; ++q) {
        float4 a = ap[q];
        float4 o;
        o.x = lrelu(fin(a.x) + gcnbf[q*4+0]);
        o.y = lrelu(fin(a.y) + gcnbf[q*4+1]);
        o.z = lrelu(fin(a.z) + gcnbf[q*4+2]);
        o.w = lrelu(fin(a.w) + gcnbf[q*4+3]);
        hp[q] = o;
    }
}

__global__ void k_final(const float* __restrict__ hacc, const float* __restrict__ gcnbf,
                        const float* __restrict__ post, const int* __restrict__ flags,
                        void* __restrict__ out, int N) {
    int n = blockIdx.x * 256 + threadIdx.x;
    if (n >= N) return;
    float v[HID];
    const float4* ap = reinterpret_cast<const float4*>(hacc + (size_t)n * HID);
    #pragma unroll
    for (int q = 0; q < 4; ++q) {
        float4 a = ap[q];
        v[q*4+0] = lrelu(fin(a.x) + gcnbf[q*4+0]);
        v[q*4+1] = lrelu(fin(a.y) + gcnbf[q*4+1]);
        v[q*4+2] = lrelu(fin(a.z) + gcnbf[q*4+2]);
        v[q*4+3] = lrelu(fin(a.w) + gcnbf[q*4+3]);
    }
    float o = post[16], an = post[33];
    #pragma unroll
    for (int j = 0; j < HID; ++j) {
        o += v[j] * post[j];
        an += v[j] * post[17 + j];
    }
    if (flags[1]) {
        float* ob = (float*)out;
        ob[n] = o;
        ob[N + n] = an;
        float* hr = ob + 2 * (size_t)N + (size_t)n * HID;
        #pragma unroll
        for (int j = 0; j < HID; ++j) hr[j] = v[j];
    } else {
        unsigned short* ob = (unsigned short*)out;
        ob[n] = f2bf(o);
        ob[N + n] = f2bf(an);
        uint4* hr = reinterpret_cast<uint4*>(ob + 2 * (size_t)N + (size_t)n * HID);
        hr[0] = pack8(v);
        hr[1] = pack8(v + 8);
    }
}

extern "C" void kernel_launch(void* const* d_in, const int* in_sizes, int n_in,
                              void* d_out, int out_size, void* d_ws, size_t ws_size,
                              hipStream_t stream) {
    const void* x    = d_in[0];
    const int*  ei   = (const int*)d_in[1];
    const void* p1W  = d_in[2];
    const void* p1b  = d_in[3];
    const void* p2W  = d_in[4];
    const void* p2b  = d_in[5];
    const void* bih  = d_in[6];
    const void* bhh  = d_in[7];
    const void* wtW  = d_in[8];
    const void* wtb  = d_in[9];
    const void* gcnb = d_in[10];
    const void* po1W = d_in[11];
    const void* po1b = d_in[12];
    const void* poaW = d_in[13];
    const void* poab = d_in[14];

    const int N = in_sizes[0] / IN_DIM;   // 100000
    const int E = in_sizes[1] / 2;        // 3200000

    float* ws = (float*)d_ws;
    float* w1q   = ws + OFF_W1F;
    float* b1f   = ws + OFF_B1F;
    float* w2t   = ws + OFF_W2T;
    float* b2f   = ws + OFF_B2F;
    float* hw    = ws + OFF_HW;
    float* gcnbf = ws + OFF_GCNB;
    float* post  = ws + OFF_POST;
    int*   flags = (int*)(ws + OFF_FLAGS);
    unsigned* bsum = (unsigned*)(ws + OFF_BSUM);
    unsigned* bpre = (unsigned*)(ws + OFF_BPRE);

    const int nb_nodes = (N + 255) / 256;
    const int nb_edges = (E + 255) / 256;
    const int nb_n8    = (int)(((long long)N * 8 + 255) / 256);
    const int nb_pre   = (N + 63) / 64;
    const int NB       = (N + 1023) / 1024;

    size_t req_csr = ((size_t)OFF_A0 + 35 * (size_t)N + (size_t)E + 64) * 4;
    size_t req_fb  = ((size_t)OFF_A0 + 33 * (size_t)N + 64) * 4;

    if (ws_size >= req_csr && NB <= 128) {
        // ================= CSR (pull) path =================
        unsigned* deg    = (unsigned*)(ws + OFF_A0);
        unsigned* rowptr = deg + N;
        float*    dinv   = (float*)(rowptr + N);
        unsigned* csr    = (unsigned*)(dinv + N);
        float*    y      = (float*)(csr + E);
        float*    h      = y + (size_t)N * HID;

        // 8-way degree replicas overlay y (8N uints <= 16N floats);
        // dead before k_xw_y writes y
        unsigned* degr = (unsigned*)y;

        hipMemsetAsync(degr, 0, (size_t)NRANGE * N * 4, stream);
        k_detect<<<1, 64, 0, stream>>>((const unsigned short*)x, ei, flags);
        k_prep_small<<<1, 256, 0, stream>>>(bih, bhh, wtW, wtb, po1W, po1b, poaW, poab,
                                            flags, hw, post);
        k_convert<<<128, 256, 0, stream>>>(p1W, p1b, p2W, p2b, gcnb, flags,
                                           w1q, b1f, w2t, b2f, gcnbf);
        k_deg_rep<<<nb_edges, 256, 0, stream>>>(ei, flags, degr, E, N);
        k_scan_block<<<NB, 1024, 0, stream>>>(degr, deg, bsum, N);
        k_scan_top<<<1, 128, 0, stream>>>(bsum, bpre, NB);
        k_scan_final<<<NB, 1024, 0, stream>>>(deg, bpre, rowptr, dinv, N);
        k_fill<<<nb_edges * NRANGE, 256, 0, stream>>>(ei, flags, rowptr, csr, E, N);
        k_pre_lds<<<nb_pre, 512, 0, stream>>>(x, w1q, b1f, w2t, b2f, flags, h, N);

        k_xw_y<<<nb_nodes, 256, 0, stream>>>(h, hw + 0, dinv, y, N);
        k_gather<<<nb_n8, 256, 0, stream>>>(rowptr, deg, csr, y, dinv, gcnbf + 0, h, N);
        k_xw_y<<<nb_nodes, 256, 0, stream>>>(h, hw + 256, dinv, y, N);
        k_gather_final<<<nb_n8, 256, 0, stream>>>(rowptr, deg, csr, y, dinv, gcnbf + 16,
                                                  post, flags, d_out, N);
    } else if (ws_size >= req_fb) {
        // ================= fallback (atomic) path =================
        float* degdinv = ws + OFF_A0;
        float* hacc    = degdinv + N;
        float* h       = hacc + (size_t)N * HID;
        void*  xw      = d_out;

        hipMemsetAsync(degdinv, 0, (size_t)N * 4, stream);
        k_detect<<<1, 64, 0, stream>>>((const unsigned short*)x, ei, flags);
        k_prep_small<<<1, 256, 0, stream>>>(bih, bhh, wtW, wtb, po1W, po1b, poaW, poab,
                                            flags, hw, post);
        k_convert<<<128, 256, 0, stream>>>(p1W, p1b, p2W, p2b, gcnb, flags,
                                           w1q, b1f, w2t, b2f, gcnbf);
        k_deg<<<nb_edges * NRANGE, 256, 0, stream>>>(ei, flags, (unsigned*)degdinv, E, N);
        k_dinv<<<nb_nodes, 256, 0, stream>>>(degdinv, N);
        k_pre_lds<<<nb_pre, 512, 0, stream>>>(x, w1q, b1f, w2t, b2f, flags, h, N);
        for (int l = 0; l < 2; ++l) {
            k_xw<<<nb_nodes, 256, 0, stream>>>(h, hw + l * 256, degdinv, flags, xw, hacc, N);
            k_scatter<<<nb_edges, 256, 0, stream>>>(ei, flags, degdinv, xw, hacc, E, N);
            if (l == 0) k_finish<<<nb_nodes, 256, 0, stream>>>(hacc, gcnbf + 0, h, N);
            else        k_final<<<nb_nodes, 256, 0, stream>>>(hacc, gcnbf + 16, post, flags, d_out, N);
        }
    } else {
        float f = 256.0f + (float)(ws_size >> 20);
        unsigned uv; __builtin_memcpy(&uv, &f, 4);
        int words = out_size / 2;
        k_sentinel<<<(words + 255) / 256, 256, 0, stream>>>((unsigned*)d_out, words, uv);
    }
}